// Round 1
// baseline (200.859 us; speedup 1.0000x reference)
//
#include <hip/hip_runtime.h>
#include <hip/hip_bf16.h>

// Problem constants (from reference): x is (32, 512) int32 in [0,16);
// pos_enc is (5000, 384) float32; output is (32, T, 384) float32 where
// T = max over batch of sum(x[b,:]).  T is recovered from out_size.

#define B 32
#define L 512
#define D 384
#define D4 (D / 4)   // 96 float4 per output row

// ---------------------------------------------------------------------------
// Kernel 1: per-row inclusive cumsum of x (32 rows x 512).  One wave per row.
// Each lane handles 8 consecutive elements; wave-level shfl_up scan.
// ---------------------------------------------------------------------------
__global__ __launch_bounds__(64) void pe_cumsum_kernel(
    const int* __restrict__ x, int* __restrict__ cs) {
  const int b = blockIdx.x;
  const int lane = threadIdx.x;  // 0..63
  const int base = b * L + lane * 8;

  const int4* xr = reinterpret_cast<const int4*>(x + base);
  int4 a = xr[0];
  int4 c = xr[1];
  int v[8] = {a.x, a.y, a.z, a.w, c.x, c.y, c.z, c.w};

  int pref[8];
  int s = 0;
#pragma unroll
  for (int k = 0; k < 8; ++k) { s += v[k]; pref[k] = s; }

  // Inclusive wave scan of per-lane sums (wave = 64 lanes on gfx950).
  int acc = s;
#pragma unroll
  for (int off = 1; off < 64; off <<= 1) {
    int n = __shfl_up(acc, off);
    if (lane >= off) acc += n;
  }
  const int offset = acc - s;  // exclusive prefix for this lane

  int4 o0 = make_int4(offset + pref[0], offset + pref[1],
                      offset + pref[2], offset + pref[3]);
  int4 o1 = make_int4(offset + pref[4], offset + pref[5],
                      offset + pref[6], offset + pref[7]);
  int4* cr = reinterpret_cast<int4*>(cs + base);
  cr[0] = o0;
  cr[1] = o1;
}

// ---------------------------------------------------------------------------
// Kernel 2: posidx[b,t] = t - starts[b, tok]  (or -1 if t >= total[b]).
// tok = searchsorted(cs[b], t, side='right') clipped to L-1.
// Binary search over the 2KB cs row (L1-resident).
// ---------------------------------------------------------------------------
__global__ __launch_bounds__(256) void pe_searchsorted_kernel(
    const int* __restrict__ x, const int* __restrict__ cs,
    int* __restrict__ posidx, int T) {
  const int b = blockIdx.y;
  const int t = blockIdx.x * 256 + threadIdx.x;
  if (t >= T) return;

  const int* csr = cs + b * L;
  const int total = csr[L - 1];

  int out = -1;
  if (t < total) {
    // first index with cs[i] > t
    int lo = 0, hi = L;
    while (lo < hi) {
      int mid = (lo + hi) >> 1;
      if (csr[mid] <= t) lo = mid + 1; else hi = mid;
    }
    int tok = lo < (L - 1) ? lo : (L - 1);
    // starts[tok] = cs[tok] - x[tok]
    out = t - (csr[tok] - x[b * L + tok]);
  }
  posidx[b * T + t] = out;
}

// ---------------------------------------------------------------------------
// Kernel 3: the writer.  Grid-stride over out_size/4 float4 elements.
// row = i / 96; gather pos_enc[posidx[row]] (only rows 0..15 ever touched,
// L1-resident) or write zeros.  Coalesced float4 stores dominate: ~190MB.
// ---------------------------------------------------------------------------
__global__ __launch_bounds__(256) void pe_gather_kernel(
    const float4* __restrict__ pe, const int* __restrict__ posidx,
    float4* __restrict__ out, int n4) {
  const int stride = gridDim.x * blockDim.x;
  for (int i = blockIdx.x * blockDim.x + threadIdx.x; i < n4; i += stride) {
    const int row = i / D4;
    const int col = i - row * D4;
    const int p = posidx[row];
    float4 v = make_float4(0.f, 0.f, 0.f, 0.f);
    if (p >= 0) v = pe[p * D4 + col];
    out[i] = v;
  }
}

// ---------------------------------------------------------------------------
extern "C" void kernel_launch(void* const* d_in, const int* in_sizes, int n_in,
                              void* d_out, int out_size, void* d_ws, size_t ws_size,
                              hipStream_t stream) {
  const int* x = (const int*)d_in[0];          // (32, 512) int32
  const float* pe = (const float*)d_in[1];     // (5000, 384) float32
  float* out = (float*)d_out;                  // (32, T, 384) float32

  const int T = out_size / (B * D);

  // ws layout: cs (32*512 int = 64KB) | posidx (32*T int)
  int* cs = (int*)d_ws;
  int* posidx = cs + B * L;

  pe_cumsum_kernel<<<B, 64, 0, stream>>>(x, cs);

  dim3 g2((T + 255) / 256, B);
  pe_searchsorted_kernel<<<g2, 256, 0, stream>>>(x, cs, posidx, T);

  const int n4 = out_size / 4;
  int blocks = (n4 + 255) / 256;
  if (blocks > 2048) blocks = 2048;
  pe_gather_kernel<<<blocks, 256, 0, stream>>>(
      (const float4*)pe, posidx, (float4*)out, n4);
}